// Round 1
// baseline (137.322 us; speedup 1.0000x reference)
//
#include <hip/hip_runtime.h>

#define NBINS 8192            // 13-bit top bits of sortable key
#define HIST_BLOCKS 1024
#define HIST_THREADS 256
#define SUM_BLOCKS 2048
#define SUM_THREADS 256

struct Control {
  unsigned bsel;        // boundary bin (13-bit)
  unsigned need;        // K - count_above
  unsigned bincount;    // elements in boundary bin
  unsigned count_above; // elements strictly above boundary bin
  float frac;           // need / bincount
};

// Monotone float -> uint map (ascending). Larger curvature -> larger key.
__device__ __forceinline__ unsigned sortable_key(float f) {
  unsigned u = __float_as_uint(f);
  return u ^ ((u & 0x80000000u) ? 0xFFFFFFFFu : 0x80000000u);
}

__global__ void __launch_bounds__(HIST_THREADS) hist_kernel(
    const float* __restrict__ cv, unsigned* __restrict__ hist,
    int nvec, int ntail) {
  __shared__ unsigned h[NBINS];
  for (int i = threadIdx.x; i < NBINS; i += blockDim.x) h[i] = 0;
  __syncthreads();

  const float4* __restrict__ c4 = (const float4*)cv;
  int idx = blockIdx.x * blockDim.x + threadIdx.x;
  int stride = gridDim.x * blockDim.x;
  for (int i = idx; i < nvec; i += stride) {
    float4 v = c4[i];
    atomicAdd(&h[sortable_key(v.x) >> 19], 1u);
    atomicAdd(&h[sortable_key(v.y) >> 19], 1u);
    atomicAdd(&h[sortable_key(v.z) >> 19], 1u);
    atomicAdd(&h[sortable_key(v.w) >> 19], 1u);
  }
  if (idx == 0) {  // scalar tail (N%4 elements) straight to global hist
    for (int i = 0; i < ntail; ++i)
      atomicAdd(&hist[sortable_key(cv[nvec * 4 + i]) >> 19], 1u);
  }
  __syncthreads();
  for (int i = threadIdx.x; i < NBINS; i += blockDim.x) {
    unsigned c = h[i];
    if (c) atomicAdd(&hist[i], c);  // skip empty bins (most are)
  }
}

// One block, 1024 threads. Suffix-scan histogram from highest key down,
// find bin where cumulative count crosses K.
__global__ void __launch_bounds__(1024) select_kernel(
    const unsigned* __restrict__ hist, Control* __restrict__ ctl, unsigned K) {
  __shared__ unsigned cnt[NBINS];
  __shared__ unsigned waveTot[16];
  __shared__ unsigned waveSuf[16];
  int tid = threadIdx.x;
  for (int i = tid; i < NBINS; i += 1024) cnt[i] = hist[i];
  __syncthreads();

  // each thread owns 8 consecutive bins
  unsigned base = tid * 8;
  unsigned c[8];
  unsigned cs = 0;
#pragma unroll
  for (int i = 0; i < 8; ++i) { c[i] = cnt[base + i]; cs += c[i]; }

  // wave-level inclusive suffix sum of chunk sums
  int lane = tid & 63;
  int wid = tid >> 6;
  unsigned incl = cs;
#pragma unroll
  for (int off = 1; off < 64; off <<= 1) {
    unsigned o = __shfl_down(incl, off);
    if (lane + off < 64) incl += o;
  }
  if (lane == 0) waveTot[wid] = incl;  // wave total
  __syncthreads();
  if (tid == 0) {
    unsigned run = 0;
    for (int w = 15; w >= 0; --w) { waveSuf[w] = run; run += waveTot[w]; }
  }
  __syncthreads();

  // count of all elements in bins strictly above this thread's chunk
  unsigned above = waveSuf[wid] + (incl - cs);
  unsigned run = above;
#pragma unroll
  for (int i = 7; i >= 0; --i) {  // bins high->low within chunk
    unsigned cc = c[i];
    if (cc && run < K && run + cc >= K) {  // unique crossing
      unsigned need = K - run;
      ctl->bsel = base + (unsigned)i;
      ctl->count_above = run;
      ctl->need = need;
      ctl->bincount = cc;
      ctl->frac = (float)((double)need / (double)cc);
    }
    run += cc;
  }
}

__global__ void __launch_bounds__(SUM_THREADS) sum_kernel(
    const float* __restrict__ xin, const float* __restrict__ tin,
    const float* __restrict__ cin, const Control* __restrict__ ctl,
    double* __restrict__ sums, int nvec, int ntail) {
  const unsigned bsel = ctl->bsel;
  const float frac = ctl->frac;

  const float4* __restrict__ x4 = (const float4*)xin;
  const float4* __restrict__ t4 = (const float4*)tin;
  const float4* __restrict__ c4 = (const float4*)cin;

  float sp = 0.f, st = 0.f, spt = 0.f;
  int idx = blockIdx.x * blockDim.x + threadIdx.x;
  int stride = gridDim.x * blockDim.x;
  for (int i = idx; i < nvec; i += stride) {
    float4 cv = c4[i];
    float4 xv = x4[i];
    float4 tv = t4[i];
#pragma unroll
    for (int j = 0; j < 4; ++j) {
      float cj = (&cv.x)[j];
      float xj = (&xv.x)[j];
      float tj = (&tv.x)[j];
      unsigned bin = sortable_key(cj) >> 19;
      float w = (bin > bsel) ? 1.f : ((bin == bsel) ? frac : 0.f);
      float p = 1.f / (1.f + __expf(-xj));  // unconditional: no divergence
      sp  += w * p;
      st  += w * tj;
      spt += w * p * tj;
    }
  }
  if (idx == 0) {  // scalar tail
    for (int i = 0; i < ntail; ++i) {
      int e = nvec * 4 + i;
      unsigned bin = sortable_key(cin[e]) >> 19;
      float w = (bin > bsel) ? 1.f : ((bin == bsel) ? frac : 0.f);
      float p = 1.f / (1.f + __expf(-xin[e]));
      sp += w * p; st += w * tin[e]; spt += w * p * tin[e];
    }
  }

  // wave reduce (64 lanes)
#pragma unroll
  for (int off = 32; off > 0; off >>= 1) {
    sp  += __shfl_down(sp, off);
    st  += __shfl_down(st, off);
    spt += __shfl_down(spt, off);
  }
  __shared__ float wsum[3][SUM_THREADS / 64];
  int lane = threadIdx.x & 63;
  int wid = threadIdx.x >> 6;
  if (lane == 0) { wsum[0][wid] = sp; wsum[1][wid] = st; wsum[2][wid] = spt; }
  __syncthreads();
  if (threadIdx.x == 0) {
    double a = 0, b = 0, c = 0;
#pragma unroll
    for (int w = 0; w < SUM_THREADS / 64; ++w) {
      a += (double)wsum[0][w]; b += (double)wsum[1][w]; c += (double)wsum[2][w];
    }
    atomicAdd(&sums[0], a);
    atomicAdd(&sums[1], b);
    atomicAdd(&sums[2], c);
  }
}

__global__ void finalize_kernel(const double* __restrict__ sums,
                                float* __restrict__ out) {
  double Sp = sums[0], St = sums[1], I = sums[2];
  double dice = (2.0 * I + 1.0) / (Sp + St + 1.0);
  out[0] = (float)(1.0 - dice);
}

extern "C" void kernel_launch(void* const* d_in, const int* in_sizes, int n_in,
                              void* d_out, int out_size, void* d_ws, size_t ws_size,
                              hipStream_t stream) {
  const float* d_inputs  = (const float*)d_in[0];
  const float* d_targets = (const float*)d_in[1];
  const float* d_curv    = (const float*)d_in[2];
  float* out = (float*)d_out;

  int N = in_sizes[2];
  unsigned K = (unsigned)(0.4 * (double)N);  // matches Python int(R*N)

  unsigned* hist = (unsigned*)d_ws;
  Control* ctl = (Control*)((char*)d_ws + NBINS * 4);
  double* sums = (double*)((char*)d_ws + NBINS * 4 + 32);

  // zero hist + control + sums every call (harness doesn't re-poison)
  hipMemsetAsync(d_ws, 0, NBINS * 4 + 32 + 3 * sizeof(double), stream);

  int nvec = N / 4;
  int ntail = N - nvec * 4;

  hist_kernel<<<HIST_BLOCKS, HIST_THREADS, 0, stream>>>(d_curv, hist, nvec, ntail);
  select_kernel<<<1, 1024, 0, stream>>>(hist, ctl, K);
  sum_kernel<<<SUM_BLOCKS, SUM_THREADS, 0, stream>>>(d_inputs, d_targets, d_curv,
                                                     ctl, sums, nvec, ntail);
  finalize_kernel<<<1, 1, 0, stream>>>(sums, out);
}